// Round 13
// baseline (130.100 us; speedup 1.0000x reference)
//
#include <hip/hip_runtime.h>

#define NB 8
#define N1 8192
#define N2 2048
#define C1 256
#define C2 512
#define CO 768   // C1 + C2
#define CCH 4    // channels per interp block (fallback path)

typedef float f2 __attribute__((ext_vector_type(2)));
typedef float f4 __attribute__((ext_vector_type(4)));

// ws (fused path): ft = kfeat^T, (B, N2, C2) floats = 32 MB.
// ws (fallback path): nn_idx/nn_w packed = 2 MB. Runtime branch on ws_size.

// ---------------------------------------------------------------------------
// ASM-PINNED arithmetic (R8..R12-validated bit sequences) — verbatim.
// ---------------------------------------------------------------------------
#define NRM2(X, Y, Z) ({                                                   \
    float _s, _t;                                                          \
    asm("v_mul_f32 %0, %2, %2\n\t"                                         \
        "v_mul_f32 %1, %3, %3\n\t"                                         \
        "v_add_f32 %0, %0, %1\n\t"                                         \
        "v_mul_f32 %1, %4, %4\n\t"                                         \
        "v_add_f32 %0, %0, %1"                                             \
        : "=&v"(_s), "=&v"(_t) : "v"(X), "v"(Y), "v"(Z));                  \
    _s; })

#define PKD2(X01, Y01, Z01, K01, QXD, QYD, QZD, QQD, M2) ({                \
    f2 _d, _s;                                                             \
    asm("v_pk_mul_f32 %0, %2, %6\n\t"      /* kx*qx per half        */     \
        "v_pk_fma_f32 %0, %3, %7, %0\n\t"  /* + ky*qy               */     \
        "v_pk_fma_f32 %0, %4, %8, %0\n\t"  /* + kz*qz -> dot        */     \
        "v_pk_add_f32 %1, %5, %9\n\t"      /* kk+qq                 */     \
        "v_pk_fma_f32 %0, %0, %10, %1"     /* d2 = dot*(-2)+(kk+qq) */     \
        : "=&v"(_d), "=&v"(_s)                                             \
        : "v"(X01), "v"(Y01), "v"(Z01), "v"(K01),                          \
          "v"(QXD), "v"(QYD), "v"(QZD), "v"(QQD), "v"(M2));                \
    _d; })

// Branchless top-3 insert — verbatim R12 (validated).
#define INS(S, D2, J) do {                                                 \
        float _v = (D2);                                                   \
        bool c2 = _v < b2##S, c1 = _v < b1##S, c0 = _v < b0##S;            \
        i2##S = c2 ? (c1 ? i1##S : (J)) : i2##S;                           \
        b2##S = c2 ? (c1 ? b1##S : _v) : b2##S;                            \
        i1##S = c0 ? i0##S : (c1 ? (J) : i1##S);                           \
        b1##S = c0 ? b0##S : (c1 ? _v : b1##S);                            \
        i0##S = c0 ? (J) : i0##S;                                          \
        b0##S = c0 ? _v : b0##S;                                           \
    } while (0)

// ---------------------------------------------------------------------------
// Transpose kfeat (B, C2, N2) -> ft (B, N2, C2). Padded 64x65 LDS tile;
// both global accesses coalesced; (lj+j)%32 banks = 2-way = free.
// ---------------------------------------------------------------------------
__global__ __launch_bounds__(256) void transpose_kf(
    const float* __restrict__ kfeat,
    float* __restrict__ ft)
{
    __shared__ float t[64][65];
    const int jb = (blockIdx.x & 31) * 64;
    const int cb = ((blockIdx.x >> 5) & 7) * 64;
    const int b  = blockIdx.x >> 8;
    const float* src = kfeat + (size_t)b * C2 * N2;
    float* dst = ft + (size_t)b * N2 * C2;
    const int lj = threadIdx.x & 63, hi = threadIdx.x >> 6;
    #pragma unroll
    for (int k = 0; k < 16; ++k) {
        const int c = hi * 16 + k;
        t[c][lj] = src[(size_t)(cb + c) * N2 + jb + lj];
    }
    __syncthreads();
    #pragma unroll
    for (int k = 0; k < 16; ++k) {
        const int j = hi * 16 + k;
        dst[(size_t)(jb + j) * C2 + cb + lj] = t[lj][j];
    }
}

// ---------------------------------------------------------------------------
// FUSED kernel: per (batch, 128-query tile): knn scan (verbatim R12
// structure) -> merge into LDS -> interp from ft (L2-resident, XCD-pinned
// batch) via [128c][131q] LDS transpose tile -> coalesced out writes ->
// folded qfeat copy. LDS aliasing: stile reuses the scan/merge regions,
// separated by __syncthreads (pd/pi disjoint from sk, since waves write pd
// while others still scan).
// ---------------------------------------------------------------------------
typedef float PdArr[128][3];
typedef int   PiArr[128][3];

__global__ __launch_bounds__(512, 4) void fused_all(
    const float* __restrict__ qxyz,   // (B, 3, N1)
    const float* __restrict__ kxyz,   // (B, 3, N2)
    const float* __restrict__ qfeat,  // (B, C1, N1)
    const float* __restrict__ ft,     // (B, N2, C2) transposed
    float* __restrict__ out)          // (B, CO, N1)
{
    // carve: [0,32K) sk arrays; [32K,44K) pd; [44K,56.3K) pi; stile = [0,67K)
    __shared__ __align__(16) char smem[128 * 131 * 4];
    __shared__ int4   nni[128];
    __shared__ float4 nnw[128];
    float* skx = (float*)(smem);
    float* sky = (float*)(smem + 8192);
    float* skz = (float*)(smem + 16384);
    float* skk = (float*)(smem + 24576);
    PdArr* pd  = (PdArr*)(smem + 32768);
    PiArr* pi  = (PiArr*)(smem + 45056);
    float (*stile)[131] = (float(*)[131])smem;

    const int b    = blockIdx.x & 7;        // XCD-pinned batch
    const int tile = blockIdx.x >> 3;       // 0..63
    const int n0   = tile * 128;
    const int tid  = threadIdx.x;
    const int w    = tid >> 6, lane = tid & 63;

    // ---- stage keys with pinned |k|^2 (verbatim R12) ----
    const float* kb = kxyz + (size_t)b * 3 * N2;
    for (int j = tid; j < N2; j += 512) {
        float x = kb[j], y = kb[N2 + j], z = kb[2 * N2 + j];
        skx[j] = x; sky[j] = y; skz[j] = z;
        skk[j] = NRM2(x, y, z);
    }
    __syncthreads();

    // ---- scan: two queries per lane (verbatim R12) ----
    const int na = n0 + lane, nb2 = n0 + 64 + lane;
    const float* qb = qxyz + (size_t)b * 3 * N1;
    const float qxA = qb[na], qyA = qb[N1 + na], qzA = qb[2 * N1 + na];
    const float qxB = qb[nb2], qyB = qb[N1 + nb2], qzB = qb[2 * N1 + nb2];
    const float qqA = NRM2(qxA, qyA, qzA);
    const float qqB = NRM2(qxB, qyB, qzB);

    f2 qxdA, qydA, qzdA, qqdA, qxdB, qydB, qzdB, qqdB, m2;
    qxdA.x = qxA; qxdA.y = qxA;  qydA.x = qyA; qydA.y = qyA;
    qzdA.x = qzA; qzdA.y = qzA;  qqdA.x = qqA; qqdA.y = qqA;
    qxdB.x = qxB; qxdB.y = qxB;  qydB.x = qyB; qydB.y = qyB;
    qzdB.x = qzB; qzdB.y = qzB;  qqdB.x = qqB; qqdB.y = qqB;
    m2.x = -2.0f; m2.y = -2.0f;

    float b0A = 3.4e38f, b1A = 3.4e38f, b2A = 3.4e38f;
    float b0B = 3.4e38f, b1B = 3.4e38f, b2B = 3.4e38f;
    int   i0A = 0, i1A = 0, i2A = 0, i0B = 0, i1B = 0, i2B = 0;

    const int jlo = w * (N2 / 8);            // 256 keys per wave-chunk
    #pragma unroll 4
    for (int g = 0; g < (N2 / 8) / 4; ++g) {
        const int jb = jlo + g * 4;
        f4 x4 = *(const f4*)&skx[jb];        // wave-uniform b128 broadcast
        f4 y4 = *(const f4*)&sky[jb];
        f4 z4 = *(const f4*)&skz[jb];
        f4 k4 = *(const f4*)&skk[jb];
        f2 dA01 = PKD2(x4.xy, y4.xy, z4.xy, k4.xy, qxdA, qydA, qzdA, qqdA, m2);
        f2 dA23 = PKD2(x4.zw, y4.zw, z4.zw, k4.zw, qxdA, qydA, qzdA, qqdA, m2);
        f2 dB01 = PKD2(x4.xy, y4.xy, z4.xy, k4.xy, qxdB, qydB, qzdB, qqdB, m2);
        f2 dB23 = PKD2(x4.zw, y4.zw, z4.zw, k4.zw, qxdB, qydB, qzdB, qqdB, m2);
        INS(A, dA01.x, jb);     INS(A, dA01.y, jb + 1);
        INS(A, dA23.x, jb + 2); INS(A, dA23.y, jb + 3);
        INS(B, dB01.x, jb);     INS(B, dB01.y, jb + 1);
        INS(B, dB23.x, jb + 2); INS(B, dB23.y, jb + 3);
    }

    (*(pd + w))[lane][0] = b0A; (*(pd + w))[lane][1] = b1A; (*(pd + w))[lane][2] = b2A;
    (*(pi + w))[lane][0] = i0A; (*(pi + w))[lane][1] = i1A; (*(pi + w))[lane][2] = i2A;
    (*(pd + w))[64 + lane][0] = b0B; (*(pd + w))[64 + lane][1] = b1B; (*(pd + w))[64 + lane][2] = b2B;
    (*(pi + w))[64 + lane][0] = i0B; (*(pi + w))[64 + lane][1] = i1B; (*(pi + w))[64 + lane][2] = i2B;
    __syncthreads();

    // ---- merge (verbatim R12 order), result -> LDS ----
    if (tid < 128) {
        float m0 = 3.4e38f, m1 = 3.4e38f, m2s = 3.4e38f;
        int   j0 = 0, j1 = 0, j2 = 0;
        #pragma unroll
        for (int c = 0; c < 8; ++c) {
            #pragma unroll
            for (int s = 0; s < 3; ++s) {
                float d = (*(pd + c))[tid][s];
                int   i = (*(pi + c))[tid][s];
                if (d < m2s) {
                    bool c0 = d < m0, c1 = d < m1;
                    m2s = c1 ? m1 : d;               j2 = c1 ? j1 : i;
                    m1 = c0 ? m0 : (c1 ? d : m1);    j1 = c0 ? j0 : (c1 ? i : j1);
                    m0 = c0 ? d : m0;                j0 = c0 ? i  : j0;
                }
            }
        }
        float d0f = fmaxf(m0, 1e-10f), d1f = fmaxf(m1, 1e-10f), d2f = fmaxf(m2s, 1e-10f);
        float v0 = __fdiv_rn(1.0f, d0f), v1 = __fdiv_rn(1.0f, d1f), v2 = __fdiv_rn(1.0f, d2f);
        float s  = __fadd_rn(__fadd_rn(v0, v1), v2);
        nni[tid] = make_int4(j0, j1, j2, 0);
        nnw[tid] = make_float4(__fdiv_rn(v0, s), __fdiv_rn(v1, s),
                               __fdiv_rn(v2, s), 0.0f);
    }
    __syncthreads();   // pd/pi dead; stile may now alias them

    // ---- interp: 4 passes of 128 channels through LDS transpose tile ----
    const float* ftb = ft + (size_t)b * N2 * C2;
    float* ob = out + (size_t)b * CO * N1;
    #pragma unroll
    for (int p = 0; p < 4; ++p) {
        const int cbase = p * 128;
        #pragma unroll 4
        for (int qi = 0; qi < 16; ++qi) {
            const int q = w * 16 + qi;           // wave-uniform
            const int4   iv = nni[q];
            const float4 wv = nnw[q];
            #pragma unroll
            for (int h = 0; h < 2; ++h) {
                const int c = h * 64 + lane;
                const float f0 = ftb[(size_t)iv.x * C2 + cbase + c];
                const float f1 = ftb[(size_t)iv.y * C2 + cbase + c];
                const float f2l = ftb[(size_t)iv.z * C2 + cbase + c];
                // validated fma order: fmaf(w2,f2, fmaf(w1,f1, mul(w0,f0)))
                stile[c][q] = fmaf(wv.z, f2l, fmaf(wv.y, f1, __fmul_rn(wv.x, f0)));
            }
        }
        __syncthreads();
        // write out: lane = query -> coalesced 256B/wave
        #pragma unroll
        for (int it = 0; it < 32; ++it) {
            const int idx = it * 512 + tid;
            const int c = idx >> 7, q = idx & 127;
            ob[(size_t)(cbase + c) * N1 + n0 + q] = stile[c][q];
        }
        __syncthreads();
    }

    // ---- folded qfeat copy (validated float4 stream) ----
    const float4* qsrc = (const float4*)(qfeat + (size_t)b * C1 * N1);
    float4*       qdst = (float4*)(out + (size_t)b * CO * N1 + (size_t)C2 * N1);
    #pragma unroll
    for (int k = 0; k < 16; ++k) {
        const size_t r = (size_t)tile * 8192 + (size_t)k * 512 + tid;
        qdst[r] = qsrc[r];
    }
}

// ===========================================================================
// FALLBACK path (ws too small for ft): R12 kernels verbatim.
// ===========================================================================
__global__ __launch_bounds__(512, 4) void knn_scan(
    const float* __restrict__ qxyz, const float* __restrict__ kxyz,
    const float* __restrict__ qfeat, int* __restrict__ nn_idx,
    float* __restrict__ nn_w, float* __restrict__ out)
{
    __shared__ __align__(16) float skx[N2];
    __shared__ __align__(16) float sky[N2];
    __shared__ __align__(16) float skz[N2];
    __shared__ __align__(16) float skk[N2];
    __shared__ float pd[8][128][3];
    __shared__ int   pi[8][128][3];

    const int b    = blockIdx.x >> 6;
    const int tile = blockIdx.x & 63;
    const int n0   = tile * 128;
    const int tid  = threadIdx.x;
    const int w    = tid >> 6, lane = tid & 63;

    const float* kb = kxyz + (size_t)b * 3 * N2;
    for (int j = tid; j < N2; j += 512) {
        float x = kb[j], y = kb[N2 + j], z = kb[2 * N2 + j];
        skx[j] = x; sky[j] = y; skz[j] = z;
        skk[j] = NRM2(x, y, z);
    }
    __syncthreads();

    const int na = n0 + lane, nb2 = n0 + 64 + lane;
    const float* qb = qxyz + (size_t)b * 3 * N1;
    const float qxA = qb[na], qyA = qb[N1 + na], qzA = qb[2 * N1 + na];
    const float qxB = qb[nb2], qyB = qb[N1 + nb2], qzB = qb[2 * N1 + nb2];
    const float qqA = NRM2(qxA, qyA, qzA);
    const float qqB = NRM2(qxB, qyB, qzB);

    f2 qxdA, qydA, qzdA, qqdA, qxdB, qydB, qzdB, qqdB, m2;
    qxdA.x = qxA; qxdA.y = qxA;  qydA.x = qyA; qydA.y = qyA;
    qzdA.x = qzA; qzdA.y = qzA;  qqdA.x = qqA; qqdA.y = qqA;
    qxdB.x = qxB; qxdB.y = qxB;  qydB.x = qyB; qydB.y = qyB;
    qzdB.x = qzB; qzdB.y = qzB;  qqdB.x = qqB; qqdB.y = qqB;
    m2.x = -2.0f; m2.y = -2.0f;

    float b0A = 3.4e38f, b1A = 3.4e38f, b2A = 3.4e38f;
    float b0B = 3.4e38f, b1B = 3.4e38f, b2B = 3.4e38f;
    int   i0A = 0, i1A = 0, i2A = 0, i0B = 0, i1B = 0, i2B = 0;

    const int jlo = w * (N2 / 8);
    #pragma unroll 4
    for (int g = 0; g < (N2 / 8) / 4; ++g) {
        const int jb = jlo + g * 4;
        f4 x4 = *(const f4*)&skx[jb];
        f4 y4 = *(const f4*)&sky[jb];
        f4 z4 = *(const f4*)&skz[jb];
        f4 k4 = *(const f4*)&skk[jb];
        f2 dA01 = PKD2(x4.xy, y4.xy, z4.xy, k4.xy, qxdA, qydA, qzdA, qqdA, m2);
        f2 dA23 = PKD2(x4.zw, y4.zw, z4.zw, k4.zw, qxdA, qydA, qzdA, qqdA, m2);
        f2 dB01 = PKD2(x4.xy, y4.xy, z4.xy, k4.xy, qxdB, qydB, qzdB, qqdB, m2);
        f2 dB23 = PKD2(x4.zw, y4.zw, z4.zw, k4.zw, qxdB, qydB, qzdB, qqdB, m2);
        INS(A, dA01.x, jb);     INS(A, dA01.y, jb + 1);
        INS(A, dA23.x, jb + 2); INS(A, dA23.y, jb + 3);
        INS(B, dB01.x, jb);     INS(B, dB01.y, jb + 1);
        INS(B, dB23.x, jb + 2); INS(B, dB23.y, jb + 3);
    }

    pd[w][lane][0] = b0A; pd[w][lane][1] = b1A; pd[w][lane][2] = b2A;
    pi[w][lane][0] = i0A; pi[w][lane][1] = i1A; pi[w][lane][2] = i2A;
    pd[w][64 + lane][0] = b0B; pd[w][64 + lane][1] = b1B; pd[w][64 + lane][2] = b2B;
    pi[w][64 + lane][0] = i0B; pi[w][64 + lane][1] = i1B; pi[w][64 + lane][2] = i2B;
    __syncthreads();

    if (tid < 128) {
        float m0 = 3.4e38f, m1 = 3.4e38f, m2s = 3.4e38f;
        int   j0 = 0, j1 = 0, j2 = 0;
        #pragma unroll
        for (int c = 0; c < 8; ++c) {
            #pragma unroll
            for (int s = 0; s < 3; ++s) {
                float d = pd[c][tid][s];
                int   i = pi[c][tid][s];
                if (d < m2s) {
                    bool c0 = d < m0, c1 = d < m1;
                    m2s = c1 ? m1 : d;               j2 = c1 ? j1 : i;
                    m1 = c0 ? m0 : (c1 ? d : m1);    j1 = c0 ? j0 : (c1 ? i : j1);
                    m0 = c0 ? d : m0;                j0 = c0 ? i  : j0;
                }
            }
        }
        float d0f = fmaxf(m0, 1e-10f), d1f = fmaxf(m1, 1e-10f), d2f = fmaxf(m2s, 1e-10f);
        float v0 = __fdiv_rn(1.0f, d0f), v1 = __fdiv_rn(1.0f, d1f), v2 = __fdiv_rn(1.0f, d2f);
        float s  = __fadd_rn(__fadd_rn(v0, v1), v2);
        const size_t g = (size_t)b * N1 + n0 + tid;
        *(int4*)  &nn_idx[g * 4] = make_int4(j0, j1, j2, 0);
        *(float4*)&nn_w  [g * 4] = make_float4(__fdiv_rn(v0, s), __fdiv_rn(v1, s),
                                               __fdiv_rn(v2, s), 0.0f);
    }

    const float4* qsrc = (const float4*)(qfeat + (size_t)b * C1 * N1);
    float4*       qdst = (float4*)(out + (size_t)b * CO * N1 + (size_t)C2 * N1);
    #pragma unroll
    for (int k = 0; k < 16; ++k) {
        const size_t r = (size_t)tile * 8192 + (size_t)k * 512 + tid;
        qdst[r] = qsrc[r];
    }
}

__global__ __launch_bounds__(256) void interp4(
    const float* __restrict__ kfeat, const int* __restrict__ nn_idx,
    const float* __restrict__ nn_w, float* __restrict__ out)
{
    __shared__ __align__(16) float4 skf[N2];
    const int b     = blockIdx.x & 7;
    const int cg    = blockIdx.x >> 3;
    const int cbase = cg * CCH;
    const int tid   = threadIdx.x;

    const float* kf = kfeat + (size_t)b * C2 * N2 + (size_t)cbase * N2;
    for (int j = tid; j < N2; j += 256) {
        skf[j] = make_float4(kf[j], kf[N2 + j], kf[2 * N2 + j], kf[3 * N2 + j]);
    }
    __syncthreads();

    const int*   ib = nn_idx + (size_t)b * N1 * 4;
    const float* wb = nn_w   + (size_t)b * N1 * 4;
    float* ob = out + (size_t)b * CO * N1;

    #pragma unroll 4
    for (int t = 0; t < N1 / 256; ++t) {
        const int n = t * 256 + tid;
        const int4   iv = *(const int4*)  &ib[(size_t)n * 4];
        const float4 wv = *(const float4*)&wb[(size_t)n * 4];
        const float4 f0 = skf[iv.x];
        const float4 f1 = skf[iv.y];
        const float4 f2v = skf[iv.z];
        ob[(size_t)(cbase + 0) * N1 + n] =
            fmaf(wv.z, f2v.x, fmaf(wv.y, f1.x, __fmul_rn(wv.x, f0.x)));
        ob[(size_t)(cbase + 1) * N1 + n] =
            fmaf(wv.z, f2v.y, fmaf(wv.y, f1.y, __fmul_rn(wv.x, f0.y)));
        ob[(size_t)(cbase + 2) * N1 + n] =
            fmaf(wv.z, f2v.z, fmaf(wv.y, f1.z, __fmul_rn(wv.x, f0.z)));
        ob[(size_t)(cbase + 3) * N1 + n] =
            fmaf(wv.z, f2v.w, fmaf(wv.y, f1.w, __fmul_rn(wv.x, f0.w)));
    }
}

extern "C" void kernel_launch(void* const* d_in, const int* in_sizes, int n_in,
                              void* d_out, int out_size, void* d_ws, size_t ws_size,
                              hipStream_t stream) {
    const float* qxyz  = (const float*)d_in[0];
    const float* kxyz  = (const float*)d_in[1];
    const float* qfeat = (const float*)d_in[2];
    const float* kfeat = (const float*)d_in[3];
    float* out = (float*)d_out;

    const size_t ft_bytes = (size_t)NB * N2 * C2 * 4;   // 32 MB
    if (ws_size >= ft_bytes) {
        float* ft = (float*)d_ws;
        transpose_kf<<<NB * 8 * 32, 256, 0, stream>>>(kfeat, ft);
        fused_all<<<NB * (N1 / 128), 512, 0, stream>>>(qxyz, kxyz, qfeat, ft, out);
    } else {
        int*   nn_idx = (int*)d_ws;
        float* nn_w   = (float*)d_ws + (size_t)4 * NB * N1;
        knn_scan<<<NB * (N1 / 128), 512, 0, stream>>>(qxyz, kxyz, qfeat,
                                                      nn_idx, nn_w, out);
        interp4<<<NB * (C2 / CCH), 256, 0, stream>>>(kfeat, nn_idx, nn_w, out);
    }
}

// Round 14
// 110.985 us; speedup vs baseline: 1.1722x; 1.1722x over previous
//
#include <hip/hip_runtime.h>

#define NB 8
#define N1 8192
#define N2 2048
#define C1 256
#define C2 512
#define CO 768   // C1 + C2
#define CCH 4    // channels per interp block

typedef float f2 __attribute__((ext_vector_type(2)));
typedef float f4 __attribute__((ext_vector_type(4)));

// ws: keys4 (B*N2 float4 = 256 KB) | nn_idx (B*N1*4 ints = 1 MB) |
//     nn_w (B*N1*4 floats = 1 MB). Total 2.25 MB.  (R11-exact layout)

// ---------------------------------------------------------------------------
// ASM-PINNED arithmetic — VERBATIM R11 (validated 112.3 us, absmax 0.015625):
//   nrm2 = (x*x + y*y) + z*z            (stepwise rn)
//   dot  = fma(z,qz, fma(y,qy, x*qx))   (fma chain)
//   d2   = (qq + kk) - 2*dot            (stepwise rn)
// ---------------------------------------------------------------------------
#define NRM2(X, Y, Z) ({                                                   \
    float _s, _t;                                                          \
    asm("v_mul_f32 %0, %2, %2\n\t"                                         \
        "v_mul_f32 %1, %3, %3\n\t"                                         \
        "v_add_f32 %0, %0, %1\n\t"                                         \
        "v_mul_f32 %1, %4, %4\n\t"                                         \
        "v_add_f32 %0, %0, %1"                                             \
        : "=&v"(_s), "=&v"(_t) : "v"(X), "v"(Y), "v"(Z));                  \
    _s; })

#define PKD2(X01, Y01, Z01, K01, QXD, QYD, QZD, QQD, M2) ({                \
    f2 _d, _s;                                                             \
    asm("v_pk_mul_f32 %0, %2, %6\n\t"      /* kx*qx per half        */     \
        "v_pk_fma_f32 %0, %3, %7, %0\n\t"  /* + ky*qy               */     \
        "v_pk_fma_f32 %0, %4, %8, %0\n\t"  /* + kz*qz -> dot        */     \
        "v_pk_add_f32 %1, %5, %9\n\t"      /* kk+qq                 */     \
        "v_pk_fma_f32 %0, %0, %10, %1"     /* d2 = dot*(-2)+(kk+qq) */     \
        : "=&v"(_d), "=&v"(_s)                                             \
        : "v"(X01), "v"(Y01), "v"(Z01), "v"(K01),                          \
          "v"(QXD), "v"(QYD), "v"(QZD), "v"(QQD), "v"(M2));                \
    _d; })

// Branchy top-3 insert — VERBATIM R11 (validated).
#define INS(S, D2, J) do {                                                 \
        float _v = (D2);                                                   \
        if (_v < b2##S) {                                                  \
            bool c0 = _v < b0##S, c1 = _v < b1##S;                         \
            b2##S = c1 ? b1##S : _v;                                       \
            i2##S = c1 ? i1##S : (J);                                      \
            b1##S = c0 ? b0##S : (c1 ? _v : b1##S);                        \
            i1##S = c0 ? i0##S : (c1 ? (J) : i1##S);                       \
            b0##S = c0 ? _v : b0##S;                                       \
            i0##S = c0 ? (J) : i0##S;                                      \
        } } while (0)

// ---------------------------------------------------------------------------
// Pack keys to float4(x,y,z,|k|^2) — VERBATIM R11.
// ---------------------------------------------------------------------------
__global__ __launch_bounds__(256) void pack_keys(
    const float* __restrict__ kxyz,   // (B, 3, N2)
    float4* __restrict__ keys4)       // (B, N2)
{
    const int b = blockIdx.x >> 3;
    const int j = (blockIdx.x & 7) * 256 + threadIdx.x;
    const float* kb = kxyz + (size_t)b * 3 * N2;
    float x = kb[j], y = kb[N2 + j], z = kb[2 * N2 + j];
    keys4[(size_t)b * N2 + j] = make_float4(x, y, z, NRM2(x, y, z));
}

// ---------------------------------------------------------------------------
// KNN — VERBATIM R11 (validated 112.3us config): 512 thr = 8 waves = 128
// queries (2/lane), keys staged from keys4, wave w scans chunk ascending,
// 8-chunk merge by tid<128 (chunk asc, rank asc, strict-<) == jax.lax.top_k,
// folded qfeat copy.
// ---------------------------------------------------------------------------
__global__ __launch_bounds__(512, 4) void knn_scan(
    const float* __restrict__ qxyz,   // (B, 3, N1)
    const float4* __restrict__ keys4, // (B, N2) packed
    const float* __restrict__ qfeat,  // (B, C1, N1)
    int*   __restrict__ nn_idx,       // (B*N1*4) packed
    float* __restrict__ nn_w,         // (B*N1*4) packed
    float* __restrict__ out)          // (B, CO, N1)
{
    __shared__ __align__(16) float skx[N2];
    __shared__ __align__(16) float sky[N2];
    __shared__ __align__(16) float skz[N2];
    __shared__ __align__(16) float skk[N2];
    __shared__ float pd[8][128][3];    // 12 KB
    __shared__ int   pi[8][128][3];    // 12 KB

    const int b    = blockIdx.x >> 6;       // 64 tiles of 128 queries
    const int tile = blockIdx.x & 63;
    const int n0   = tile * 128;
    const int tid  = threadIdx.x;
    const int w    = tid >> 6, lane = tid & 63;

    // stage keys (coalesced float4 from packed ws; values bit-identical)
    const float4* kb4 = keys4 + (size_t)b * N2;
    for (int j = tid; j < N2; j += 512) {
        float4 k4 = kb4[j];
        skx[j] = k4.x; sky[j] = k4.y; skz[j] = k4.z; skk[j] = k4.w;
    }
    __syncthreads();

    // two queries per lane
    const int na = n0 + lane, nb = n0 + 64 + lane;
    const float* qb = qxyz + (size_t)b * 3 * N1;
    const float qxA = qb[na], qyA = qb[N1 + na], qzA = qb[2 * N1 + na];
    const float qxB = qb[nb], qyB = qb[N1 + nb], qzB = qb[2 * N1 + nb];
    const float qqA = NRM2(qxA, qyA, qzA);
    const float qqB = NRM2(qxB, qyB, qzB);

    f2 qxdA, qydA, qzdA, qqdA, qxdB, qydB, qzdB, qqdB, m2;
    qxdA.x = qxA; qxdA.y = qxA;  qydA.x = qyA; qydA.y = qyA;
    qzdA.x = qzA; qzdA.y = qzA;  qqdA.x = qqA; qqdA.y = qqA;
    qxdB.x = qxB; qxdB.y = qxB;  qydB.x = qyB; qydB.y = qyB;
    qzdB.x = qzB; qzdB.y = qzB;  qqdB.x = qqB; qqdB.y = qqB;
    m2.x = -2.0f; m2.y = -2.0f;

    float b0A = 3.4e38f, b1A = 3.4e38f, b2A = 3.4e38f;
    float b0B = 3.4e38f, b1B = 3.4e38f, b2B = 3.4e38f;
    int   i0A = 0, i1A = 0, i2A = 0, i0B = 0, i1B = 0, i2B = 0;

    const int jlo = w * (N2 / 8);            // 256 keys per wave-chunk
    #pragma unroll 4
    for (int g = 0; g < (N2 / 8) / 4; ++g) {
        const int jb = jlo + g * 4;
        f4 x4 = *(const f4*)&skx[jb];        // wave-uniform b128 broadcast
        f4 y4 = *(const f4*)&sky[jb];
        f4 z4 = *(const f4*)&skz[jb];
        f4 k4 = *(const f4*)&skk[jb];
        f2 dA01 = PKD2(x4.xy, y4.xy, z4.xy, k4.xy, qxdA, qydA, qzdA, qqdA, m2);
        f2 dA23 = PKD2(x4.zw, y4.zw, z4.zw, k4.zw, qxdA, qydA, qzdA, qqdA, m2);
        f2 dB01 = PKD2(x4.xy, y4.xy, z4.xy, k4.xy, qxdB, qydB, qzdB, qqdB, m2);
        f2 dB23 = PKD2(x4.zw, y4.zw, z4.zw, k4.zw, qxdB, qydB, qzdB, qqdB, m2);
        INS(A, dA01.x, jb);     INS(A, dA01.y, jb + 1);
        INS(A, dA23.x, jb + 2); INS(A, dA23.y, jb + 3);
        INS(B, dB01.x, jb);     INS(B, dB01.y, jb + 1);
        INS(B, dB23.x, jb + 2); INS(B, dB23.y, jb + 3);
    }

    pd[w][lane][0] = b0A; pd[w][lane][1] = b1A; pd[w][lane][2] = b2A;
    pi[w][lane][0] = i0A; pi[w][lane][1] = i1A; pi[w][lane][2] = i2A;
    pd[w][64 + lane][0] = b0B; pd[w][64 + lane][1] = b1B; pd[w][64 + lane][2] = b2B;
    pi[w][64 + lane][0] = i0B; pi[w][64 + lane][1] = i1B; pi[w][64 + lane][2] = i2B;
    __syncthreads();

    if (tid < 128) {
        float m0 = 3.4e38f, m1 = 3.4e38f, m2s = 3.4e38f;
        int   j0 = 0, j1 = 0, j2 = 0;
        #pragma unroll
        for (int c = 0; c < 8; ++c) {
            #pragma unroll
            for (int s = 0; s < 3; ++s) {
                float d = pd[c][tid][s];
                int   i = pi[c][tid][s];
                if (d < m2s) {
                    bool c0 = d < m0, c1 = d < m1;
                    m2s = c1 ? m1 : d;               j2 = c1 ? j1 : i;
                    m1 = c0 ? m0 : (c1 ? d : m1);    j1 = c0 ? j0 : (c1 ? i : j1);
                    m0 = c0 ? d : m0;                j0 = c0 ? i  : j0;
                }
            }
        }
        // weights: mirror reference op order (R8-validated, packed store)
        float d0f = fmaxf(m0, 1e-10f), d1f = fmaxf(m1, 1e-10f), d2f = fmaxf(m2s, 1e-10f);
        float v0 = __fdiv_rn(1.0f, d0f), v1 = __fdiv_rn(1.0f, d1f), v2 = __fdiv_rn(1.0f, d2f);
        float s  = __fadd_rn(__fadd_rn(v0, v1), v2);
        const size_t g = (size_t)b * N1 + n0 + tid;
        *(int4*)  &nn_idx[g * 4] = make_int4(j0, j1, j2, 0);
        *(float4*)&nn_w  [g * 4] = make_float4(__fdiv_rn(v0, s), __fdiv_rn(v1, s),
                                               __fdiv_rn(v2, s), 0.0f);
    }

    // Folded qfeat copy (validated float4 stream; rides knn's idle HBM).
    const float4* qsrc = (const float4*)(qfeat + (size_t)b * C1 * N1);
    float4*       qdst = (float4*)(out + (size_t)b * CO * N1 + (size_t)C2 * N1);
    #pragma unroll
    for (int k = 0; k < 16; ++k) {
        const size_t r = (size_t)tile * 8192 + (size_t)k * 512 + tid;
        qdst[r] = qsrc[r];
    }
}

// ---------------------------------------------------------------------------
// Interp, 2-stage SOFTWARE PIPELINE (the one changed component vs R11).
// Same math/layout as validated interp4; only load scheduling differs:
// nn[t+2] global load issued 2 iters early, LDS gathers for t+1 issued 1
// iter early — hides the ~200-500cyc nn-load and ~120cyc LDS latency under
// the current iteration's fma+stores. Named registers only (no runtime-
// indexed arrays -> no scratch). Tail garbage regs are never dereferenced:
// at t=30, ivN stays =ivB (valid); at t=31 no gather reads occur.
// ---------------------------------------------------------------------------
__global__ __launch_bounds__(256) void interp5(
    const float* __restrict__ kfeat,  // (B, C2, N2)
    const int*   __restrict__ nn_idx, // packed stride-4
    const float* __restrict__ nn_w,   // packed stride-4
    float* __restrict__ out)          // (B, CO, N1)
{
    __shared__ __align__(16) float4 skf[N2];   // 32 KB
    const int b     = blockIdx.x & 7;       // XCD-pinned batch
    const int cg    = blockIdx.x >> 3;      // 0..127
    const int cbase = cg * CCH;
    const int tid   = threadIdx.x;

    const float* kf = kfeat + (size_t)b * C2 * N2 + (size_t)cbase * N2;
    for (int j = tid; j < N2; j += 256) {
        skf[j] = make_float4(kf[j], kf[N2 + j], kf[2 * N2 + j], kf[3 * N2 + j]);
    }
    __syncthreads();

    const int*   ib = nn_idx + (size_t)b * N1 * 4;
    const float* wb = nn_w   + (size_t)b * N1 * 4;
    float* ob = out + (size_t)b * CO * N1;

    // pipeline prologue: nn for t=0,1; gathers for t=0
    int4   ivA = *(const int4*)  &ib[(size_t)(0 * 256 + tid) * 4];
    float4 wvA = *(const float4*)&wb[(size_t)(0 * 256 + tid) * 4];
    int4   ivB = *(const int4*)  &ib[(size_t)(1 * 256 + tid) * 4];
    float4 wvB = *(const float4*)&wb[(size_t)(1 * 256 + tid) * 4];
    float4 g0 = skf[ivA.x], g1 = skf[ivA.y], g2 = skf[ivA.z];

    #pragma unroll
    for (int t = 0; t < 32; ++t) {
        // stage 2: issue nn load for t+2
        int4 ivN = ivB; float4 wvN = wvB;
        if (t + 2 < 32) {
            ivN = *(const int4*)  &ib[(size_t)((t + 2) * 256 + tid) * 4];
            wvN = *(const float4*)&wb[(size_t)((t + 2) * 256 + tid) * 4];
        }
        // stage 1: issue LDS gathers for t+1
        float4 h0 = g0, h1 = g1, h2 = g2;
        if (t + 1 < 32) { h0 = skf[ivB.x]; h1 = skf[ivB.y]; h2 = skf[ivB.z]; }
        // stage 0: compute & store t (validated fma order)
        const int n = t * 256 + tid;
        ob[(size_t)(cbase + 0) * N1 + n] =
            fmaf(wvA.z, g2.x, fmaf(wvA.y, g1.x, __fmul_rn(wvA.x, g0.x)));
        ob[(size_t)(cbase + 1) * N1 + n] =
            fmaf(wvA.z, g2.y, fmaf(wvA.y, g1.y, __fmul_rn(wvA.x, g0.y)));
        ob[(size_t)(cbase + 2) * N1 + n] =
            fmaf(wvA.z, g2.z, fmaf(wvA.y, g1.z, __fmul_rn(wvA.x, g0.z)));
        ob[(size_t)(cbase + 3) * N1 + n] =
            fmaf(wvA.z, g2.w, fmaf(wvA.y, g1.w, __fmul_rn(wvA.x, g0.w)));
        // rotate pipeline registers
        ivA = ivB; wvA = wvB; ivB = ivN; wvB = wvN;
        g0 = h0; g1 = h1; g2 = h2;
    }
}

extern "C" void kernel_launch(void* const* d_in, const int* in_sizes, int n_in,
                              void* d_out, int out_size, void* d_ws, size_t ws_size,
                              hipStream_t stream) {
    const float* qxyz  = (const float*)d_in[0];
    const float* kxyz  = (const float*)d_in[1];
    const float* qfeat = (const float*)d_in[2];
    const float* kfeat = (const float*)d_in[3];
    float* out = (float*)d_out;

    float*  ws     = (float*)d_ws;
    float4* keys4  = (float4*)ws;                                // 65536 f
    int*    nn_idx = (int*)(ws + (size_t)4 * NB * N2);           // 262144 i
    float*  nn_w   = ws + (size_t)4 * NB * N2 + (size_t)4 * NB * N1;

    pack_keys<<<NB * (N2 / 256), 256, 0, stream>>>(kxyz, keys4);
    knn_scan<<<NB * (N1 / 128), 512, 0, stream>>>(qxyz, keys4, qfeat,
                                                  nn_idx, nn_w, out);
    interp5<<<NB * (C2 / CCH), 256, 0, stream>>>(kfeat, nn_idx, nn_w, out);
}